// Round 1
// 1737.585 us; speedup vs baseline: 1.4185x; 1.4185x over previous
//
#include <hip/hip_runtime.h>
#include <stdint.h>
#include <stddef.h>

// ---------------------------------------------------------------------------
// InceptionResNet sparse-conv block, MI355X (gfx950).
//   N=500000 pts, C=128, K=27 neighbor offsets. Inputs/out f32 (adaptive bf16).
// R4: conv3 kernels are latency/MLP-bound (27 serial idx->gather->MFMA chains;
// compiler serialized gathers, VGPR=76). New conv3p_k: 2-deep register
// pipeline (idx prefetch 2 ahead, gather double-buffer 1 ahead, B-frags
// preloaded BEFORE next gathers so in-order vmcnt never drains the prefetch).
// Mask packed into nbr sign bit (pack_nbr) to shorten the dependent chain.
// ---------------------------------------------------------------------------

typedef __attribute__((ext_vector_type(8))) short bf16x8;
typedef __attribute__((ext_vector_type(4))) float f32x4;

__device__ __forceinline__ float bf2f(uint16_t u) {
  union { uint32_t i; float f; } v; v.i = ((uint32_t)u) << 16; return v.f;
}
__device__ __forceinline__ uint16_t f2bf(float f) {
  union { float f; uint32_t i; } v; v.f = f;
  return (uint16_t)((v.i + 0x7fffu + ((v.i >> 16) & 1u)) >> 16);  // RNE
}
__device__ __forceinline__ bf16x8 zero8() {
  bf16x8 z = {0, 0, 0, 0, 0, 0, 0, 0};
  return z;
}
__device__ __forceinline__ bf16x8 cvt8(const float* p) {
  f32x4 u = *(const f32x4*)p, w = *(const f32x4*)(p + 4);
  bf16x8 r;
  r[0] = (short)f2bf(u[0]); r[1] = (short)f2bf(u[1]);
  r[2] = (short)f2bf(u[2]); r[3] = (short)f2bf(u[3]);
  r[4] = (short)f2bf(w[0]); r[5] = (short)f2bf(w[1]);
  r[6] = (short)f2bf(w[2]); r[7] = (short)f2bf(w[3]);
  return r;
}

// ---------------- ws layout (bytes) ----------------
// bf16 elems [0, 199680): transposed weights
//   W00t 32x128 @0 | W02t 64x32 @4096 | W01t 27x32x32 @6144
//   W10t 27x32x128 @33792 | W11t 27x64x32 @144384
// 399360: float biasF[224] (b00@0,b01@32,b02@64,b10@128,b11@160)
// 401408: int flags[4]  [0]=mask-is-bytes, [1]=x-is-f32
// 524288:    hA (N x 32 bf16, 32 MB)
// 34078720:  hB (N x 32 bf16, 32 MB)
// 67633152:  xb (N x 128 bf16, 128 MB)        [if ws_size permits]
// 67633152 + N*256: nbrm (N x 27 int, 54 MB)  [if ws_size permits]
#define WS_BIASF 399360
#define WS_FLAGS 401408
#define WS_HA    524288
#define WS_HB    34078720
#define WS_XB    67633152

__global__ void detect_modes(const uint32_t* __restrict__ xw,
                             const uint32_t* __restrict__ mw,
                             int* __restrict__ flags) {
  __shared__ int shc[256];
  __shared__ uint32_t shm[256];
  int c = 0;
  uint32_t mv = 0;
  for (int i = threadIdx.x; i < 4096; i += 256) {
    uint32_t e = (xw[i] >> 7) & 0xFFu;   // exponent bits of LOW uint16 half
    c += (e >= 110 && e <= 135) ? 1 : 0;
  }
  for (int i = threadIdx.x; i < 2048; i += 256) mv |= mw[i];
  shc[threadIdx.x] = c;
  shm[threadIdx.x] = mv;
  __syncthreads();
  for (int s = 128; s > 0; s >>= 1) {
    if ((int)threadIdx.x < s) {
      shc[threadIdx.x] += shc[threadIdx.x + s];
      shm[threadIdx.x] |= shm[threadIdx.x + s];
    }
    __syncthreads();
  }
  if (threadIdx.x == 0) {
    flags[0] = (shm[0] > 1u) ? 1 : 0;      // byte-packed mask
    flags[1] = (shc[0] < 2048) ? 1 : 0;    // low halves not bf16-like => f32
    flags[2] = 0;
  }
}

__global__ __launch_bounds__(256) void prep_weights(
    const void* __restrict__ W00, const void* __restrict__ W01,
    const void* __restrict__ W02, const void* __restrict__ W10,
    const void* __restrict__ W11, const void* __restrict__ b00,
    const void* __restrict__ b01, const void* __restrict__ b02,
    const void* __restrict__ b10, const void* __restrict__ b11,
    uint16_t* __restrict__ wt, float* __restrict__ biasF,
    const int* __restrict__ flags) {
  const int f32 = flags[1];
  auto rd = [&](const void* p, int i) -> float {
    return f32 ? ((const float*)p)[i] : bf2f(((const uint16_t*)p)[i]);
  };
  int i = blockIdx.x * 256 + threadIdx.x;
  if (i < 4096) {                       // W00: [128][32] -> [32][128]
    int co = i >> 7, ci = i & 127;
    wt[i] = f2bf(rd(W00, ci * 32 + co)); return;
  }
  i -= 4096;
  if (i < 2048) {                       // W02: [32][64] -> [64][32]
    int co = i >> 5, ci = i & 31;
    wt[4096 + co * 32 + ci] = f2bf(rd(W02, ci * 64 + co)); return;
  }
  i -= 2048;
  if (i < 27648) {                      // W01: [27][32][32] -> T
    int k = i >> 10, r = i & 1023, co = r >> 5, ci = r & 31;
    wt[6144 + k * 1024 + co * 32 + ci] = f2bf(rd(W01, k * 1024 + ci * 32 + co)); return;
  }
  i -= 27648;
  if (i < 110592) {                     // W10: [27][128][32] -> [27][32][128]
    int k = i >> 12, r = i & 4095, co = r >> 7, ci = r & 127;
    wt[33792 + k * 4096 + co * 128 + ci] = f2bf(rd(W10, k * 4096 + ci * 32 + co)); return;
  }
  i -= 110592;
  if (i < 55296) {                      // W11: [27][32][64] -> [27][64][32]
    int k = i >> 11, r = i & 2047, co = r >> 5, ci = r & 31;
    wt[144384 + k * 2048 + co * 32 + ci] = f2bf(rd(W11, k * 2048 + ci * 64 + co)); return;
  }
  i -= 55296;
  if (i < 224) {
    float v;
    if (i < 32)        v = rd(b00, i);
    else if (i < 64)   v = rd(b01, i - 32);
    else if (i < 128)  v = rd(b02, i - 64);
    else if (i < 160)  v = rd(b10, i - 128);
    else               v = rd(b11, i - 160);
    biasF[i] = v;
  }
}

// Pack mask into nbr sign bit: nbrm[i] = nbr[i] | (mask ? 0x80000000 : 0)
__global__ __launch_bounds__(256) void pack_nbr(
    const int* __restrict__ nbr, const uint8_t* __restrict__ mask8,
    const int* __restrict__ mask32, int* __restrict__ nbrm, int total,
    const int* __restrict__ flags) {
  int i = blockIdx.x * 256 + threadIdx.x;
  if (i >= total) return;
  const int mmode = flags[0];
  int idx = nbr[i];
  bool mk = mmode ? (mask8[i] != 0) : (mask32[i] != 0);
  nbrm[i] = mk ? (idx | (int)0x80000000) : idx;
}

template <bool FDYN>
__device__ __forceinline__ bf16x8 loadA8(const void* f, size_t elem, int xf32) {
  if (FDYN && xf32) return cvt8((const float*)f + elem);
  return *(const bf16x8*)((const uint16_t*)f + elem);
}

template <bool RELU, int ROFF>
__device__ __forceinline__ void epi_store(void* outv, const void* xr, int of32,
                                          size_t p, int col, int COUT, float v,
                                          const float* biasF) {
  v += biasF[col];
  if (RELU) v = fmaxf(v, 0.f);
  if (ROFF >= 0) {
    size_t oi = p * 128 + ROFF + col;
    if (of32) {
      float r = ((const float*)xr)[oi];
      ((float*)outv)[oi] = v + r;
    } else {
      float r = bf2f(((const uint16_t*)xr)[oi]);
      ((uint16_t*)outv)[oi] = f2bf(v + r);
    }
  } else {
    ((uint16_t*)outv)[p * COUT + col] = f2bf(v);
  }
}

// ---------------- 1x1 conv (per-point matmul), optional fused cast ----------
template <int CIN, int COUT, bool RELU, int ROFF, bool FDYN, bool CAST>
__global__ __launch_bounds__(256) void conv1_k(
    const void* __restrict__ f, const uint16_t* __restrict__ wt,
    const float* __restrict__ biasF, const void* __restrict__ xr,
    void* __restrict__ outv, int n, const int* __restrict__ flags,
    uint16_t* __restrict__ xb) {
  constexpr int S = CIN / 32;
  constexpr int T = COUT / 16;
  const int xf32 = FDYN ? flags[1] : 0;
  const int of32 = (ROFF >= 0) ? flags[1] : 0;
  const int lane = threadIdx.x & 63;
  const int wid = threadIdx.x >> 6;
  const int m = lane & 15, kg = lane >> 4;
  const int tile0 = blockIdx.x * 16 + wid * 4;

  int tb[4];
  bool rowok[4];
  size_t ab[4];
#pragma unroll
  for (int mt = 0; mt < 4; ++mt) {
    tb[mt] = (tile0 + mt) * 16;
    int row = tb[mt] + m;
    rowok[mt] = row < n;
    ab[mt] = (size_t)(rowok[mt] ? row : 0) * CIN + kg * 8;
  }

  f32x4 acc[4][T];
#pragma unroll
  for (int mt = 0; mt < 4; ++mt)
#pragma unroll
    for (int t = 0; t < T; ++t) acc[mt][t] = {0.f, 0.f, 0.f, 0.f};

#pragma unroll
  for (int s = 0; s < S; ++s) {
    bf16x8 a[4];
#pragma unroll
    for (int mt = 0; mt < 4; ++mt) {
      a[mt] = rowok[mt] ? loadA8<FDYN>(f, ab[mt] + s * 32, xf32) : zero8();
      if constexpr (CAST) {
        if (rowok[mt]) *(bf16x8*)(xb + ab[mt] + s * 32) = a[mt];
      }
    }
#pragma unroll
    for (int t = 0; t < T; ++t) {
      bf16x8 b = *(const bf16x8*)(wt + (size_t)(t * 16 + m) * CIN + s * 32 + kg * 8);
#pragma unroll
      for (int mt = 0; mt < 4; ++mt)
        acc[mt][t] = __builtin_amdgcn_mfma_f32_16x16x32_bf16(a[mt], b, acc[mt][t], 0, 0, 0);
    }
  }

#pragma unroll
  for (int mt = 0; mt < 4; ++mt) {
    if (tb[mt] >= n) continue;
#pragma unroll
    for (int t = 0; t < T; ++t) {
#pragma unroll
      for (int r = 0; r < 4; ++r) {
        int p = tb[mt] + kg * 4 + r;
        if (p >= n) continue;
        epi_store<RELU, ROFF>(outv, xr, of32, (size_t)p, t * 16 + m, COUT,
                              acc[mt][t][r], biasF);
      }
    }
  }
}

// ---------------- 3x3x3 sparse conv, 2-deep pipelined (bf16 gathers) --------
// Pipeline invariants (in-order vmcnt): B-frags for k are issued BEFORE the
// gathers for k+1, so the wait before MFMA(k) leaves the k+1 gathers (and the
// k+2 index loads) in flight.
template <int CIN, int COUT, int MT, bool RELU, int ROFF, bool PACKED>
__global__ __launch_bounds__(256) void conv3p_k(
    const uint16_t* __restrict__ f, const int* __restrict__ nbrm,
    const uint8_t* __restrict__ mask8, const int* __restrict__ mask32,
    const uint16_t* __restrict__ wt, const float* __restrict__ biasF,
    const void* __restrict__ xr, void* __restrict__ outv, int n,
    const int* __restrict__ flags) {
  constexpr int S = CIN / 32;
  constexpr int T = COUT / 16;
  const int mmode = PACKED ? 0 : flags[0];
  const int of32 = (ROFF >= 0) ? flags[1] : 0;
  const int lane = threadIdx.x & 63;
  const int wid = threadIdx.x >> 6;
  const int m = lane & 15, kg = lane >> 4;
  const int tile0 = (blockIdx.x * 4 + wid) * MT;

  int tb[MT];
  bool rowok[MT];
  int nb[MT];
#pragma unroll
  for (int mt = 0; mt < MT; ++mt) {
    tb[mt] = (tile0 + mt) * 16;
    int row = tb[mt] + m;
    rowok[mt] = row < n;
    nb[mt] = (rowok[mt] ? row : 0) * 27;
  }

  f32x4 acc[MT][T];
#pragma unroll
  for (int mt = 0; mt < MT; ++mt)
#pragma unroll
    for (int t = 0; t < T; ++t) acc[mt][t] = {0.f, 0.f, 0.f, 0.f};

  const uint16_t* wb = wt + (size_t)m * CIN + (size_t)kg * 8;

  int iA[MT], iB[MT], mA[MT], mB[MT];
  bf16x8 aA[MT][S], aB[MT][S];
  bf16x8 bA[T * S], bB[T * S];

  auto LOADIDX = [&](int (&ii)[MT], int (&mm)[MT], int k) {
#pragma unroll
    for (int mt = 0; mt < MT; ++mt) {
      int off = nb[mt] + k;
      ii[mt] = nbrm[off];
      if (!PACKED) mm[mt] = mmode ? (int)mask8[off] : mask32[off];
    }
  };
  auto GATHER = [&](bf16x8 (&a)[MT][S], const int (&ii)[MT],
                    const int (&mm)[MT]) {
#pragma unroll
    for (int mt = 0; mt < MT; ++mt) {
      bool mk;
      int idx;
      if (PACKED) { mk = rowok[mt] && (ii[mt] < 0); idx = ii[mt] & 0x7fffffff; }
      else        { mk = rowok[mt] && (mm[mt] != 0); idx = ii[mt]; }
      if (mk) {
        size_t be = (size_t)idx * CIN + (size_t)kg * 8;
#pragma unroll
        for (int s = 0; s < S; ++s)
          a[mt][s] = *(const bf16x8*)(f + be + s * 32);
      } else {
#pragma unroll
        for (int s = 0; s < S; ++s) a[mt][s] = zero8();
      }
    }
  };
  auto LOADB = [&](bf16x8 (&bb)[T * S], int k) {
    const uint16_t* wk = wb + (size_t)k * COUT * CIN;
#pragma unroll
    for (int t = 0; t < T; ++t)
#pragma unroll
      for (int s = 0; s < S; ++s)
        bb[t * S + s] = *(const bf16x8*)(wk + (size_t)(t * 16) * CIN + s * 32);
  };
  auto MFMA = [&](const bf16x8 (&a)[MT][S], const bf16x8 (&bb)[T * S]) {
#pragma unroll
    for (int t = 0; t < T; ++t)
#pragma unroll
      for (int s = 0; s < S; ++s)
#pragma unroll
        for (int mt = 0; mt < MT; ++mt)
          acc[mt][t] = __builtin_amdgcn_mfma_f32_16x16x32_bf16(
              a[mt][s], bb[t * S + s], acc[mt][t], 0, 0, 0);
  };

  // Prologue: idx for k=0,1; B for k=0; gathers for k=0.
  LOADIDX(iA, mA, 0);
  LOADIDX(iB, mB, 1);
  LOADB(bA, 0);
  GATHER(aA, iA, mA);

#pragma unroll 1
  for (int k = 0; k < 26; k += 2) {
    LOADIDX(iA, mA, k + 2);      // idx for k+2 (k+2 <= 26 always)
    LOADB(bB, k + 1);            // B for k+1 (before the k+1 gathers!)
    GATHER(aB, iB, mB);          // gathers k+1 (idx already landed)
    MFMA(aA, bA);                // k — leaves aB/iA/bB in flight
    if (k + 3 < 27) LOADIDX(iB, mB, k + 3);
    LOADB(bA, k + 2);            // B for k+2 (before the k+2 gathers!)
    GATHER(aA, iA, mA);          // gathers k+2
    MFMA(aB, bB);                // k+1 — leaves aA/iB/bA in flight
  }
  MFMA(aA, bA);                  // k=26 tail

#pragma unroll
  for (int mt = 0; mt < MT; ++mt) {
    if (tb[mt] >= n) continue;
#pragma unroll
    for (int t = 0; t < T; ++t) {
#pragma unroll
      for (int r = 0; r < 4; ++r) {
        int p = tb[mt] + kg * 4 + r;
        if (p >= n) continue;
        epi_store<RELU, ROFF>(outv, xr, of32, (size_t)p, t * 16 + m, COUT,
                              acc[mt][t][r], biasF);
      }
    }
  }
}

// ---------------- legacy 3x3x3 conv (fallback path only) --------------------
template <int CIN, int COUT, bool RELU, int ROFF, bool FDYN>
__global__ __launch_bounds__(256) void conv3_k(
    const void* __restrict__ f, const int* __restrict__ nbr,
    const uint8_t* __restrict__ mask8, const int* __restrict__ mask32,
    const uint16_t* __restrict__ wt, const float* __restrict__ biasF,
    const void* __restrict__ xr, void* __restrict__ outv, int n,
    const int* __restrict__ flags) {
  constexpr int S = CIN / 32;
  constexpr int T = COUT / 16;
  const int mmode = flags[0];
  const int xf32 = FDYN ? flags[1] : 0;
  const int of32 = (ROFF >= 0) ? flags[1] : 0;
  const int lane = threadIdx.x & 63;
  const int wid = threadIdx.x >> 6;
  const int m = lane & 15, kg = lane >> 4;
  const int tile0 = blockIdx.x * 16 + wid * 4;

  int tb[4];
  bool rowok[4];
  size_t nb[4];
#pragma unroll
  for (int mt = 0; mt < 4; ++mt) {
    tb[mt] = (tile0 + mt) * 16;
    int row = tb[mt] + m;
    rowok[mt] = row < n;
    nb[mt] = (size_t)(rowok[mt] ? row : 0) * 27;
  }

  f32x4 acc[4][T];
#pragma unroll
  for (int mt = 0; mt < 4; ++mt)
#pragma unroll
    for (int t = 0; t < T; ++t) acc[mt][t] = {0.f, 0.f, 0.f, 0.f};

#pragma unroll 1
  for (int k = 0; k < 27; ++k) {
    bf16x8 a[4][S];
#pragma unroll
    for (int mt = 0; mt < 4; ++mt) {
      bool mk = false;
      int idx = 0;
      if (rowok[mt]) {
        size_t off = nb[mt] + k;
        idx = nbr[off];
        mk = mmode ? (mask8[off] != 0) : (mask32[off] != 0);
      }
      if (mk) {
        size_t be = (size_t)idx * CIN + kg * 8;
#pragma unroll
        for (int s = 0; s < S; ++s) a[mt][s] = loadA8<FDYN>(f, be + s * 32, xf32);
      } else {
#pragma unroll
        for (int s = 0; s < S; ++s) a[mt][s] = zero8();
      }
    }
    const uint16_t* wk = wt + (size_t)k * COUT * CIN + (size_t)m * CIN + kg * 8;
#pragma unroll
    for (int t = 0; t < T; ++t) {
#pragma unroll
      for (int s = 0; s < S; ++s) {
        bf16x8 b = *(const bf16x8*)(wk + (size_t)t * 16 * CIN + s * 32);
#pragma unroll
        for (int mt = 0; mt < 4; ++mt)
          acc[mt][t] = __builtin_amdgcn_mfma_f32_16x16x32_bf16(a[mt][s], b, acc[mt][t], 0, 0, 0);
      }
    }
  }

#pragma unroll
  for (int mt = 0; mt < 4; ++mt) {
    if (tb[mt] >= n) continue;
#pragma unroll
    for (int t = 0; t < T; ++t) {
#pragma unroll
      for (int r = 0; r < 4; ++r) {
        int p = tb[mt] + kg * 4 + r;
        if (p >= n) continue;
        epi_store<RELU, ROFF>(outv, xr, of32, (size_t)p, t * 16 + m, COUT,
                              acc[mt][t][r], biasF);
      }
    }
  }
}

extern "C" void kernel_launch(void* const* d_in, const int* in_sizes, int n_in,
                              void* d_out, int out_size, void* d_ws, size_t ws_size,
                              hipStream_t stream) {
  const void* x     = d_in[0];
  const int*  nbr   = (const int*)d_in[1];
  const uint8_t* mask8  = (const uint8_t*)d_in[2];
  const int*     mask32 = (const int*)d_in[2];

  char* ws = (char*)d_ws;
  uint16_t* wt    = (uint16_t*)ws;
  float*    biasF = (float*)(ws + WS_BIASF);
  int*      flags = (int*)(ws + WS_FLAGS);
  uint16_t* hA    = (uint16_t*)(ws + WS_HA);
  uint16_t* hB    = (uint16_t*)(ws + WS_HB);
  uint16_t* xb    = (uint16_t*)(ws + WS_XB);

  const int n = in_sizes[0] / 128;
  const int tiles = (n + 15) / 16;
  const int grid = (tiles + 15) / 16;        // legacy kernels: 16 tiles/block
  const int g128 = (n + 127) / 128;          // conv3p MT=2: 128 rows/block
  const int g256 = (n + 255) / 256;          // conv3p MT=4: 256 rows/block
  const int total = n * 27;

  const bool have_xb = ws_size >= (size_t)WS_XB + (size_t)n * 256;
  const size_t nbrm_off = (size_t)WS_XB + (size_t)n * 256;
  const bool have_nbrm = have_xb && ws_size >= nbrm_off + (size_t)n * 108;
  int* nbrm = (int*)(ws + nbrm_off);

  detect_modes<<<1, 256, 0, stream>>>((const uint32_t*)d_in[0],
                                      (const uint32_t*)d_in[2], flags);
  if (have_nbrm)
    pack_nbr<<<(total + 255) / 256, 256, 0, stream>>>(nbr, mask8, mask32, nbrm,
                                                      total, flags);
  prep_weights<<<781, 256, 0, stream>>>(d_in[3], d_in[5], d_in[7], d_in[9], d_in[11],
                                        d_in[4], d_in[6], d_in[8], d_in[10], d_in[12],
                                        wt, biasF, flags);

  if (have_xb) {
    // h0 = relu(x @ W00 + b00), fused cast x -> xb (bf16, L3-resident)
    conv1_k<128, 32, true, -1, true, true><<<grid, 256, 0, stream>>>(
        x, wt + 0, biasF + 0, nullptr, hA, n, flags, xb);
    if (have_nbrm) {
      // h0b = relu(conv3(h0, W01) + b01)
      conv3p_k<32, 32, 4, true, -1, true><<<g256, 256, 0, stream>>>(
          hA, nbrm, nullptr, nullptr, wt + 6144, biasF + 32, nullptr, hB, n, flags);
      // h1 = relu(conv3(xb, W10) + b10)
      conv3p_k<128, 32, 2, true, -1, true><<<g128, 256, 0, stream>>>(
          xb, nbrm, nullptr, nullptr, wt + 33792, biasF + 128, nullptr, hA, n, flags);
    } else {
      conv3p_k<32, 32, 4, true, -1, false><<<g256, 256, 0, stream>>>(
          hA, nbr, mask8, mask32, wt + 6144, biasF + 32, nullptr, hB, n, flags);
      conv3p_k<128, 32, 2, true, -1, false><<<g128, 256, 0, stream>>>(
          xb, nbr, mask8, mask32, wt + 33792, biasF + 128, nullptr, hA, n, flags);
    }
    // out[:, 0:64] = h0b @ W02 + b02 + x[:, 0:64]
    conv1_k<32, 64, false, 0, false, false><<<grid, 256, 0, stream>>>(
        hB, wt + 4096, biasF + 64, x, d_out, n, flags, nullptr);
    // out[:, 64:128] = conv3(h1, W11) + b11 + x[:, 64:128]
    if (have_nbrm)
      conv3p_k<32, 64, 2, false, 64, true><<<g128, 256, 0, stream>>>(
          hA, nbrm, nullptr, nullptr, wt + 144384, biasF + 160, x, d_out, n, flags);
    else
      conv3p_k<32, 64, 2, false, 64, false><<<g128, 256, 0, stream>>>(
          hA, nbr, mask8, mask32, wt + 144384, biasF + 160, x, d_out, n, flags);
  } else {
    // Fallback (R2 path): gather f32 x directly, legacy kernels
    conv1_k<128, 32, true, -1, true, false><<<grid, 256, 0, stream>>>(
        x, wt + 0, biasF + 0, nullptr, hA, n, flags, nullptr);
    conv3_k<32, 32, true, -1, false><<<grid, 256, 0, stream>>>(
        hA, nbr, mask8, mask32, wt + 6144, biasF + 32, nullptr, hB, n, flags);
    conv3_k<128, 32, true, -1, true><<<grid, 256, 0, stream>>>(
        x, nbr, mask8, mask32, wt + 33792, biasF + 128, nullptr, hA, n, flags);
    conv1_k<32, 64, false, 0, false, false><<<grid, 256, 0, stream>>>(
        hB, wt + 4096, biasF + 64, x, d_out, n, flags, nullptr);
    conv3_k<32, 64, false, 64, false><<<grid, 256, 0, stream>>>(
        hA, nbr, mask8, mask32, wt + 144384, biasF + 160, x, d_out, n, flags);
  }
}